// Round 3
// baseline (428.003 us; speedup 1.0000x reference)
//
#include <hip/hip_runtime.h>
#include <hip/hip_bf16.h>

// BertCRFTagger — B=32, S=512, H=1024, T=32.
//  K1 emis_part:   logits partial sums (K split across 2 blocks/row-group),
//                  512 blocks x 256 thr = 2 blocks/CU (R2 was 1/CU, 89% idle).
//  K2 softmax_num: log_softmax + softmax + CRF numerator contributions
//                  (atomicAdd into numb/lenw; start_trans here, end_trans in K4).
//  K3 chunk:       per (b,chunk-of-16-steps) 32x32 transfer matrix, ONE 32-lane
//                  group PER ROW, all-register shfl-broadcast matmul. No LDS,
//                  no barriers. Rescale every 8 steps (range <= 16^8 ~ 4e9, safe).
//  K4 phase2:      one wave per batch, prefetched chunk-matrix sweep (R2 design)
//                  + end_trans[tags[len-1]] finalize, atomicAdd -> out.

#define Bb 32
#define Ss 512
#define Hh 1024
#define Tt 32
#define NROWS (Bb*Ss)          // 16384
#define NCHUNK 32
#define CHUNK_L 16
#define PARTN ((size_t)NROWS * Tt)   // 524288 floats per K-half partial

// ---------------- K1: emissions partial GEMV ----------------
// blockIdx: rowgroup = bx>>1 (64 rows), kh = bx&1 (K half of 512).
// 4 waves split each staged 64-h chunk; lane == row; W rows via s_load (uniform).
__global__ __launch_bounds__(256) void emis_part_kernel(
    const float* __restrict__ hidden, const float* __restrict__ W,
    float* __restrict__ part) {
  __shared__ __align__(16) float hid[64 * 68];     // stride 68 = 4 mod 32: b128-safe
  __shared__ __align__(16) float red[4 * 64 * 33]; // [wave][row][t]

  const int tid = threadIdx.x;
  const int wv = __builtin_amdgcn_readfirstlane(tid >> 6);
  const int lane = tid & 63;  // row within group
  const int rowgroup = blockIdx.x >> 1;
  const int kh = blockIdx.x & 1;
  const int row0 = rowgroup * 64;
  const int kbase = kh * 512;

  float acc[32];
#pragma unroll
  for (int t = 0; t < 32; ++t) acc[t] = 0.f;

  for (int c = 0; c < 8; ++c) {  // 8 chunks of 64 h
#pragma unroll
    for (int p = 0; p < 4; ++p) {
      int f = tid + 256 * p;      // float4 slot
      int r = f >> 4, q4 = f & 15;
      const float4 v = *(const float4*)(hidden + (size_t)(row0 + r) * Hh + kbase + c * 64 + q4 * 4);
      *(float4*)&hid[r * 68 + q4 * 4] = v;
    }
    __syncthreads();
#pragma unroll
    for (int q = 0; q < 4; ++q) {           // 4x ds_read_b128 per thread
      const float4 hv = *(const float4*)&hid[lane * 68 + 16 * wv + 4 * q];
      const float hvv[4] = {hv.x, hv.y, hv.z, hv.w};
#pragma unroll
      for (int u = 0; u < 4; ++u) {
        const int h = 16 * wv + 4 * q + u;  // wave-uniform
        const float* wrow = W + (size_t)(kbase + c * 64 + h) * Tt;  // -> s_load
#pragma unroll
        for (int t = 0; t < 32; ++t) acc[t] = fmaf(hvv[u], wrow[t], acc[t]);
      }
    }
    __syncthreads();
  }
#pragma unroll
  for (int t = 0; t < 32; ++t) red[(wv * 64 + lane) * 33 + t] = acc[t];
  __syncthreads();
  // sum 4 wave-partials, write coalesced partial logits (no bias yet)
#pragma unroll
  for (int p = 0; p < 8; ++p) {
    int e = tid + 256 * p;        // 0..2047
    int r = e >> 5, t = e & 31;
    float v = red[r * 33 + t] + red[(64 + r) * 33 + t] +
              red[(128 + r) * 33 + t] + red[(192 + r) * 33 + t];
    part[(size_t)kh * PARTN + (size_t)row0 * Tt + e] = v;
  }
}

// ---------------- K2: softmax + numerator ----------------
// grid 2048 x 256: wave handles 2 rows (32 lanes/row, lane j = tag).
__global__ __launch_bounds__(256) void softmax_num_kernel(
    const float* __restrict__ part, const float* __restrict__ bias,
    const float* __restrict__ start_trans, const float* __restrict__ trans,
    const int* __restrict__ tags, const int* __restrict__ mask,
    float* __restrict__ logem, float* __restrict__ pem,
    float* __restrict__ numb, int* __restrict__ lenw) {
  const int tid = threadIdx.x;
  const int lane = tid & 63;
  const int j = lane & 31, half = lane >> 5;
  const int row = blockIdx.x * 8 + (tid >> 6) * 2 + half;

  float L = part[(size_t)row * Tt + j] + part[PARTN + (size_t)row * Tt + j] + bias[j];
  float mx = L;
#pragma unroll
  for (int d = 16; d >= 1; d >>= 1) mx = fmaxf(mx, __shfl_xor(mx, d, 32));
  float se = __expf(L - mx);
#pragma unroll
  for (int d = 16; d >= 1; d >>= 1) se += __shfl_xor(se, d, 32);
  const float corr = mx + __logf(se);
  const float lg = L - corr;
  logem[(size_t)row * Tt + j] = lg;
  pem[(size_t)row * Tt + j] = __expf(lg);

  const int m = mask[row];
  const int tg = tags[row];
  const float emit = __shfl(lg, tg, 32);
  if (j == 0) {
    const int srow = row & (Ss - 1);
    const int b = row >> 9;
    float contrib = 0.f;
    if (m) {
      contrib = emit;
      if (srow > 0) contrib += trans[tags[row - 1] * Tt + tg];
    }
    if (srow == 0) contrib += start_trans[tg];
    atomicAdd(numb + b, contrib);
    atomicAdd(lenw + b, m);
  }
}

// ---------------- K3: chunk transfer matrices, register/shfl ----------------
// 32-lane group = one matrix row. task = (b*32 + c)*32 + i; 2 rows per wave.
__global__ __launch_bounds__(256) void chunk_kernel(
    const float* __restrict__ pem, const float* __restrict__ trans,
    const int* __restrict__ lenw, float* __restrict__ ecT,
    float* __restrict__ moff) {
  const int tid = threadIdx.x;
  const int lane = tid & 63;
  const int j = lane & 31;
  const int task = (blockIdx.x * 4 + (tid >> 6)) * 2 + (lane >> 5);
  const int i = task & 31;
  const int c = (task >> 5) & 31;
  const int b = task >> 10;

  float etr[32];
#pragma unroll
  for (int k = 0; k < 32; ++k) etr[k] = __expf(trans[k * Tt + j]);

  const int len = lenw[b];           // wave-uniform
  const int t0 = 1 + c * CHUNK_L;
  int nst = (len < Ss ? len : Ss) - t0;
  nst = nst < 0 ? 0 : (nst > CHUNK_L ? CHUNK_L : nst);

  float em[CHUNK_L];
#pragma unroll
  for (int st = 0; st < CHUNK_L; ++st)
    em[st] = (st < nst) ? pem[(size_t)(b * Ss + t0 + st) * Tt + j] : 1.0f;

  float v = (i == j) ? 1.0f : 0.0f;
  float Moff = 0.f;
  for (int st = 0; st < nst; ++st) {
    float s = 0.f;
#pragma unroll
    for (int k = 0; k < 32; ++k) s = fmaf(__shfl(v, k, 32), etr[k], s);
    v = s * em[st];
    if (st == 7) {  // mid-chunk rescale
      float mm = v;
#pragma unroll
      for (int d = 16; d >= 1; d >>= 1) mm = fmaxf(mm, __shfl_xor(mm, d, 32));
      mm = fmaxf(mm, 1e-30f);
      Moff += __logf(mm);
      v *= __builtin_amdgcn_rcpf(mm);
    }
  }
  {  // final rescale -> row-max 1 invariant
    float mm = v;
#pragma unroll
    for (int d = 16; d >= 1; d >>= 1) mm = fmaxf(mm, __shfl_xor(mm, d, 32));
    mm = fmaxf(mm, 1e-30f);
    Moff += __logf(mm);
    v *= __builtin_amdgcn_rcpf(mm);
  }
  // ecT[b][c][j][i] (transposed for phase2 float4 row reads)
  ecT[(((size_t)b * NCHUNK + c) * 32 + j) * 32 + i] = v;
  if (j == 0) moff[((size_t)b * NCHUNK + c) * 32 + i] = Moff;
}

// ---------------- K4: phase-2 sweep, one wave per batch ----------------
__global__ __launch_bounds__(64) void phase2_kernel(
    const float* __restrict__ logem, const float* __restrict__ start_trans,
    const float* __restrict__ end_trans, const float* __restrict__ ecT,
    const float* __restrict__ moff, const float* __restrict__ numb,
    const int* __restrict__ lenw, const int* __restrict__ tags,
    float* __restrict__ out) {
  const int b = blockIdx.x;
  const int lane = threadIdx.x;
  const int j = lane & 31;
  __shared__ __align__(16) float qlds[32];

  const float* base = ecT + (size_t)b * NCHUNK * 32 * 32;
  const float* mbase = moff + (size_t)b * NCHUNK * 32;

  float4 M[8], N[8];
  const float* r0 = base + j * 32;
#pragma unroll
  for (int k = 0; k < 8; ++k) M[k] = *(const float4*)(r0 + 4 * k);
  float mo_cur = mbase[j];

  float al0 = start_trans[j] + logem[(size_t)b * Ss * Tt + j];
  float m0 = al0;
#pragma unroll
  for (int d = 16; d >= 1; d >>= 1) m0 = fmaxf(m0, __shfl_xor(m0, d, 32));
  float a = __expf(al0 - m0);
  float Mb = m0;
  const float eend = __expf(end_trans[j]);

  float mo_next = 0.f;
  for (int c = 0; c < NCHUNK; ++c) {
    if (c + 1 < NCHUNK) {
      const float* rn = base + ((c + 1) * 32 + j) * 32;
#pragma unroll
      for (int k = 0; k < 8; ++k) N[k] = *(const float4*)(rn + 4 * k);
      mo_next = mbase[(c + 1) * 32 + j];
    }
    float mom = mo_cur;
#pragma unroll
    for (int d = 16; d >= 1; d >>= 1) mom = fmaxf(mom, __shfl_xor(mom, d, 32));
    float q = a * __expf(mo_cur - mom);
    if (lane < 32) qlds[j] = q;
    __builtin_amdgcn_s_waitcnt(0);
    float s = 0.f;
#pragma unroll
    for (int k = 0; k < 8; ++k) {
      const float4 q4 = *(const float4*)(qlds + 4 * k);
      s = fmaf(q4.x, M[k].x, s);
      s = fmaf(q4.y, M[k].y, s);
      s = fmaf(q4.z, M[k].z, s);
      s = fmaf(q4.w, M[k].w, s);
    }
    float m = s;
#pragma unroll
    for (int d = 16; d >= 1; d >>= 1) m = fmaxf(m, __shfl_xor(m, d, 32));
    m = fmaxf(m, 1e-30f);
    a = s * __builtin_amdgcn_rcpf(m);
    Mb += mom + __logf(m);
#pragma unroll
    for (int k = 0; k < 8; ++k) M[k] = N[k];
    mo_cur = mo_next;
  }
  float z = a * eend;
#pragma unroll
  for (int d = 16; d >= 1; d >>= 1) z += __shfl_xor(z, d, 32);
  if (lane == 0) {
    const int len = lenw[b];
    const float numfull = numb[b] + end_trans[tags[b * Ss + len - 1]];
    const float denom = Mb + __logf(z);
    atomicAdd(out, -(numfull - denom) * (1.0f / 32.0f));
  }
}

extern "C" void kernel_launch(void* const* d_in, const int* in_sizes, int n_in,
                              void* d_out, int out_size, void* d_ws, size_t ws_size,
                              hipStream_t stream) {
  const float* hidden = (const float*)d_in[0];
  const float* W = (const float*)d_in[1];
  const float* bias = (const float*)d_in[2];
  const float* start_trans = (const float*)d_in[3];
  const float* end_trans = (const float*)d_in[4];
  const float* trans = (const float*)d_in[5];
  const int* tags = (const int*)d_in[6];
  const int* mask = (const int*)d_in[7];
  float* out = (float*)d_out;

  // Region A (part, later aliased by ecT+moff): 1081344 floats.
  float* part = (float*)d_ws;                        // 2*524288
  float* ecT = part;                                 // 1048576 (after part is dead)
  float* moff = part + 2 * PARTN;                    // 32768
  float* logem = moff + (size_t)Bb * NCHUNK * 32;    // 524288
  float* pem = logem + PARTN;                        // 524288
  float* numb = pem + PARTN;                         // 32
  int* lenw = (int*)(numb + Bb);                     // 32

  hipMemsetAsync(out, 0, sizeof(float), stream);
  hipMemsetAsync(numb, 0, 64 * sizeof(float), stream);  // numb + lenw
  emis_part_kernel<<<512, 256, 0, stream>>>(hidden, W, part);
  softmax_num_kernel<<<NROWS / 8, 256, 0, stream>>>(part, bias, start_trans,
                                                    trans, tags, mask, logem,
                                                    pem, numb, lenw);
  chunk_kernel<<<Bb * NCHUNK * 32 / 8, 256, 0, stream>>>(pem, trans, lenw, ecT,
                                                         moff);
  phase2_kernel<<<Bb, 64, 0, stream>>>(logem, start_trans, end_trans, ecT, moff,
                                       numb, lenw, tags, out);
}

// Round 4
// 265.841 us; speedup vs baseline: 1.6100x; 1.6100x over previous
//
#include <hip/hip_runtime.h>
#include <hip/hip_bf16.h>

// BertCRFTagger — B=32, S=512, H=1024, T=32.
//  K0 etr_prep:    etrT[j][k] = exp(trans[k][j]) ONCE (R3 recomputed 33.5M exp
//                  inside chunk_kernel ~190us of transcendental-pipe time).
//  K1 emis_part:   logits partial sums, K split across 2 blocks/row-group.
//  K2 softmax_num: log_softmax + softmax + CRF numerator; block-level LDS
//                  reduction -> ONE atomicAdd pair per block (R3 did per-row
//                  atomics: 32768 same-line device atomics = 194us serial chain).
//  K3 chunk:       per (b,16-step chunk) 32x32 transfer matrix, 32-lane group
//                  per row, register/shfl matmul, etr loaded not computed.
//  K4 phase2:      one wave per batch, prefetched chunk sweep, atomic finalize.

#define Bb 32
#define Ss 512
#define Hh 1024
#define Tt 32
#define NROWS (Bb*Ss)          // 16384
#define NCHUNK 32
#define CHUNK_L 16
#define PARTN ((size_t)NROWS * Tt)   // 524288 floats per K-half partial

// ---------------- K0: exp(trans) transpose prep ----------------
__global__ __launch_bounds__(1024) void etr_prep_kernel(
    const float* __restrict__ trans, float* __restrict__ etrT) {
  const int tid = threadIdx.x;          // 1024 = j*32+k
  const int j = tid >> 5, k = tid & 31;
  etrT[j * 32 + k] = __expf(trans[k * 32 + j]);  // etrT[j][k] = Etr[k][j]
}

// ---------------- K1: emissions partial GEMV ----------------
// blockIdx: rowgroup = bx>>1 (64 rows), kh = bx&1 (K half of 512).
__global__ __launch_bounds__(256) void emis_part_kernel(
    const float* __restrict__ hidden, const float* __restrict__ W,
    float* __restrict__ part) {
  __shared__ __align__(16) float hid[64 * 68];     // stride 68 = 4 mod 32: b128-safe
  __shared__ __align__(16) float red[4 * 64 * 33]; // [wave][row][t]

  const int tid = threadIdx.x;
  const int wv = __builtin_amdgcn_readfirstlane(tid >> 6);
  const int lane = tid & 63;  // row within group
  const int rowgroup = blockIdx.x >> 1;
  const int kh = blockIdx.x & 1;
  const int row0 = rowgroup * 64;
  const int kbase = kh * 512;

  float acc[32];
#pragma unroll
  for (int t = 0; t < 32; ++t) acc[t] = 0.f;

  for (int c = 0; c < 8; ++c) {  // 8 chunks of 64 h
#pragma unroll
    for (int p = 0; p < 4; ++p) {
      int f = tid + 256 * p;      // float4 slot
      int r = f >> 4, q4 = f & 15;
      const float4 v = *(const float4*)(hidden + (size_t)(row0 + r) * Hh + kbase + c * 64 + q4 * 4);
      *(float4*)&hid[r * 68 + q4 * 4] = v;
    }
    __syncthreads();
#pragma unroll
    for (int q = 0; q < 4; ++q) {           // 4x ds_read_b128 per thread
      const float4 hv = *(const float4*)&hid[lane * 68 + 16 * wv + 4 * q];
      const float hvv[4] = {hv.x, hv.y, hv.z, hv.w};
#pragma unroll
      for (int u = 0; u < 4; ++u) {
        const int h = 16 * wv + 4 * q + u;  // wave-uniform
        const float* wrow = W + (size_t)(kbase + c * 64 + h) * Tt;  // -> s_load
#pragma unroll
        for (int t = 0; t < 32; ++t) acc[t] = fmaf(hvv[u], wrow[t], acc[t]);
      }
    }
    __syncthreads();
  }
#pragma unroll
  for (int t = 0; t < 32; ++t) red[(wv * 64 + lane) * 33 + t] = acc[t];
  __syncthreads();
#pragma unroll
  for (int p = 0; p < 8; ++p) {
    int e = tid + 256 * p;        // 0..2047
    int r = e >> 5, t = e & 31;
    float v = red[r * 33 + t] + red[(64 + r) * 33 + t] +
              red[(128 + r) * 33 + t] + red[(192 + r) * 33 + t];
    part[(size_t)kh * PARTN + (size_t)row0 * Tt + e] = v;
  }
}

// ---------------- K2: softmax + numerator (block-reduced atomics) ----------------
// grid 2048 x 256: wave handles 2 rows (32 lanes/row). Block = 8 consecutive
// rows, all within one batch (8 | 512). ONE atomicAdd pair per block.
__global__ __launch_bounds__(256) void softmax_num_kernel(
    const float* __restrict__ part, const float* __restrict__ bias,
    const float* __restrict__ start_trans, const float* __restrict__ trans,
    const int* __restrict__ tags, const int* __restrict__ mask,
    float* __restrict__ logem, float* __restrict__ pem,
    float* __restrict__ numb, int* __restrict__ lenw) {
  __shared__ float cbuf[8];
  __shared__ int lbuf[8];
  const int tid = threadIdx.x;
  const int lane = tid & 63;
  const int j = lane & 31, half = lane >> 5;
  const int wv = tid >> 6;
  const int r8 = blockIdx.x * 8;
  const int row = r8 + wv * 2 + half;

  float L = part[(size_t)row * Tt + j] + part[PARTN + (size_t)row * Tt + j] + bias[j];
  float mx = L;
#pragma unroll
  for (int d = 16; d >= 1; d >>= 1) mx = fmaxf(mx, __shfl_xor(mx, d, 32));
  float se = __expf(L - mx);
#pragma unroll
  for (int d = 16; d >= 1; d >>= 1) se += __shfl_xor(se, d, 32);
  const float corr = mx + __logf(se);
  const float lg = L - corr;
  logem[(size_t)row * Tt + j] = lg;
  pem[(size_t)row * Tt + j] = __expf(lg);

  const int m = mask[row];
  const int tg = tags[row];               // uniform within 32-group
  const float emit = __shfl(lg, tg, 32);
  if (j == 0) {
    const int srow = row & (Ss - 1);
    float contrib = 0.f;
    if (m) {
      contrib = emit;
      if (srow > 0) contrib += trans[tags[row - 1] * Tt + tg];
    }
    if (srow == 0) contrib += start_trans[tg];
    cbuf[wv * 2 + half] = contrib;
    lbuf[wv * 2 + half] = m;
  }
  __syncthreads();
  if (tid == 0) {
    float cs = 0.f; int ls = 0;
#pragma unroll
    for (int q = 0; q < 8; ++q) { cs += cbuf[q]; ls += lbuf[q]; }
    const int b = r8 >> 9;
    atomicAdd(numb + b, cs);   // 64 atomics per address total — negligible
    atomicAdd(lenw + b, ls);
  }
}

// ---------------- K3: chunk transfer matrices, register/shfl ----------------
// 32-lane group = one matrix row. task = (b*32 + c)*32 + i; 2 tasks per wave.
__global__ __launch_bounds__(256) void chunk_kernel(
    const float* __restrict__ pem, const float* __restrict__ etrT,
    const int* __restrict__ lenw, float* __restrict__ ecT,
    float* __restrict__ moff) {
  const int tid = threadIdx.x;
  const int lane = tid & 63;
  const int j = lane & 31;
  const int task = (blockIdx.x * 4 + (tid >> 6)) * 2 + (lane >> 5);
  const int i = task & 31;
  const int c = (task >> 5) & 31;
  const int b = task >> 10;

  // lane j loads Etr[:, j] = etrT row j (contiguous, L1-resident: 4 KB total)
  float etr[32];
  const float* er = etrT + j * 32;
#pragma unroll
  for (int k4 = 0; k4 < 8; ++k4) {
    const float4 e4 = *(const float4*)(er + 4 * k4);
    etr[4 * k4 + 0] = e4.x; etr[4 * k4 + 1] = e4.y;
    etr[4 * k4 + 2] = e4.z; etr[4 * k4 + 3] = e4.w;
  }

  const int len = lenw[b];           // uniform within 32-group
  const int t0 = 1 + c * CHUNK_L;
  int nst = (len < Ss ? len : Ss) - t0;
  nst = nst < 0 ? 0 : (nst > CHUNK_L ? CHUNK_L : nst);

  float em[CHUNK_L];
#pragma unroll
  for (int st = 0; st < CHUNK_L; ++st)
    em[st] = (st < nst) ? pem[(size_t)(b * Ss + t0 + st) * Tt + j] : 1.0f;

  float v = (i == j) ? 1.0f : 0.0f;
  float Moff = 0.f;
  for (int st = 0; st < nst; ++st) {
    float s = 0.f;
#pragma unroll
    for (int k = 0; k < 32; ++k) s = fmaf(__shfl(v, k, 32), etr[k], s);
    v = s * em[st];
    if (st == 7) {  // mid-chunk rescale (underflow guard)
      float mm = v;
#pragma unroll
      for (int d = 16; d >= 1; d >>= 1) mm = fmaxf(mm, __shfl_xor(mm, d, 32));
      mm = fmaxf(mm, 1e-30f);
      Moff += __logf(mm);
      v *= __builtin_amdgcn_rcpf(mm);
    }
  }
  {  // final rescale -> row-max 1 invariant
    float mm = v;
#pragma unroll
    for (int d = 16; d >= 1; d >>= 1) mm = fmaxf(mm, __shfl_xor(mm, d, 32));
    mm = fmaxf(mm, 1e-30f);
    Moff += __logf(mm);
    v *= __builtin_amdgcn_rcpf(mm);
  }
  // ecT[b][c][j][i] (transposed for phase2 float4 row reads)
  ecT[(((size_t)b * NCHUNK + c) * 32 + j) * 32 + i] = v;
  if (j == 0) moff[((size_t)b * NCHUNK + c) * 32 + i] = Moff;
}

// ---------------- K4: phase-2 sweep, one wave per batch ----------------
__global__ __launch_bounds__(64) void phase2_kernel(
    const float* __restrict__ logem, const float* __restrict__ start_trans,
    const float* __restrict__ end_trans, const float* __restrict__ ecT,
    const float* __restrict__ moff, const float* __restrict__ numb,
    const int* __restrict__ lenw, const int* __restrict__ tags,
    float* __restrict__ out) {
  const int b = blockIdx.x;
  const int lane = threadIdx.x;
  const int j = lane & 31;
  __shared__ __align__(16) float qlds[32];

  const float* base = ecT + (size_t)b * NCHUNK * 32 * 32;
  const float* mbase = moff + (size_t)b * NCHUNK * 32;

  float4 M[8], N[8];
  const float* r0 = base + j * 32;
#pragma unroll
  for (int k = 0; k < 8; ++k) M[k] = *(const float4*)(r0 + 4 * k);
  float mo_cur = mbase[j];

  float al0 = start_trans[j] + logem[(size_t)b * Ss * Tt + j];
  float m0 = al0;
#pragma unroll
  for (int d = 16; d >= 1; d >>= 1) m0 = fmaxf(m0, __shfl_xor(m0, d, 32));
  float a = __expf(al0 - m0);
  float Mb = m0;
  const float eend = __expf(end_trans[j]);

  float mo_next = 0.f;
  for (int c = 0; c < NCHUNK; ++c) {
    if (c + 1 < NCHUNK) {
      const float* rn = base + ((c + 1) * 32 + j) * 32;
#pragma unroll
      for (int k = 0; k < 8; ++k) N[k] = *(const float4*)(rn + 4 * k);
      mo_next = mbase[(c + 1) * 32 + j];
    }
    float mom = mo_cur;
#pragma unroll
    for (int d = 16; d >= 1; d >>= 1) mom = fmaxf(mom, __shfl_xor(mom, d, 32));
    float q = a * __expf(mo_cur - mom);
    if (lane < 32) qlds[j] = q;
    __builtin_amdgcn_s_waitcnt(0);
    float s = 0.f;
#pragma unroll
    for (int k = 0; k < 8; ++k) {
      const float4 q4 = *(const float4*)(qlds + 4 * k);
      s = fmaf(q4.x, M[k].x, s);
      s = fmaf(q4.y, M[k].y, s);
      s = fmaf(q4.z, M[k].z, s);
      s = fmaf(q4.w, M[k].w, s);
    }
    float m = s;
#pragma unroll
    for (int d = 16; d >= 1; d >>= 1) m = fmaxf(m, __shfl_xor(m, d, 32));
    m = fmaxf(m, 1e-30f);
    a = s * __builtin_amdgcn_rcpf(m);
    Mb += mom + __logf(m);
#pragma unroll
    for (int k = 0; k < 8; ++k) M[k] = N[k];
    mo_cur = mo_next;
  }
  float z = a * eend;
#pragma unroll
  for (int d = 16; d >= 1; d >>= 1) z += __shfl_xor(z, d, 32);
  if (lane == 0) {
    const int len = lenw[b];
    const float numfull = numb[b] + end_trans[tags[b * Ss + len - 1]];
    const float denom = Mb + __logf(z);
    atomicAdd(out, -(numfull - denom) * (1.0f / 32.0f));
  }
}

extern "C" void kernel_launch(void* const* d_in, const int* in_sizes, int n_in,
                              void* d_out, int out_size, void* d_ws, size_t ws_size,
                              hipStream_t stream) {
  const float* hidden = (const float*)d_in[0];
  const float* W = (const float*)d_in[1];
  const float* bias = (const float*)d_in[2];
  const float* start_trans = (const float*)d_in[3];
  const float* end_trans = (const float*)d_in[4];
  const float* trans = (const float*)d_in[5];
  const int* tags = (const int*)d_in[6];
  const int* mask = (const int*)d_in[7];
  float* out = (float*)d_out;

  // Region A (part, later aliased by ecT): part dead after K2, ecT written in K3.
  float* part = (float*)d_ws;                        // 2*524288
  float* ecT = part;                                 // 1048576 (aliases part)
  float* moff = part + 2 * PARTN;                    // 32768
  float* logem = moff + (size_t)Bb * NCHUNK * 32;    // 524288
  float* pem = logem + PARTN;                        // 524288
  float* numb = pem + PARTN;                         // 32
  int* lenw = (int*)(numb + Bb);                     // 32
  float* etrT = (float*)(lenw + Bb);                 // 1024

  hipMemsetAsync(out, 0, sizeof(float), stream);
  hipMemsetAsync(numb, 0, 64 * sizeof(float), stream);  // numb + lenw
  etr_prep_kernel<<<1, 1024, 0, stream>>>(trans, etrT);
  emis_part_kernel<<<512, 256, 0, stream>>>(hidden, W, part);
  softmax_num_kernel<<<NROWS / 8, 256, 0, stream>>>(part, bias, start_trans,
                                                    trans, tags, mask, logem,
                                                    pem, numb, lenw);
  chunk_kernel<<<Bb * NCHUNK * 32 / 8, 256, 0, stream>>>(pem, etrT, lenw, ecT,
                                                         moff);
  phase2_kernel<<<Bb, 64, 0, stream>>>(logem, start_trans, end_trans, ecT, moff,
                                       numb, lenw, tags, out);
}

// Round 5
// 192.864 us; speedup vs baseline: 2.2192x; 1.3784x over previous
//
#include <hip/hip_runtime.h>
#include <hip/hip_bf16.h>

// BertCRFTagger — B=32, S=512, H=1024, T=32.
//  K1 emis_part:   logits partial sums, K split across 2 blocks/row-group.
//  K2 softmax_num: log_softmax + softmax + CRF numerator (block-reduced atomics).
//  K3 chunk:       MFMA rewrite. R4 was DS-pipe bound: 512 ds_bpermute/wave
//                  x 16384 waves x 6.4cyc = 87.5us (measured 87.7). Now ONE WAVE
//                  PER CHUNK (1024 waves), P = 4 16x16 tiles, 4x
//                  mfma_f32_16x16x32_bf16 per step, LDS roundtrip remaps
//                  C-layout -> A-layout between steps. em folded into B cols.
//                  No rescale needed in-chunk (row-max >= ~48^-16 = 1e-27 > fp32 min).
//  K4 phase2:      one wave per batch, prefetched chunk sweep, atomic finalize.

#define Bb 32
#define Ss 512
#define Hh 1024
#define Tt 32
#define NROWS (Bb*Ss)          // 16384
#define NCHUNK 32
#define CHUNK_L 16
#define PARTN ((size_t)NROWS * Tt)   // 524288 floats per K-half partial

typedef __attribute__((ext_vector_type(8))) short bf16x8;
typedef __attribute__((ext_vector_type(4))) float f32x4;

__device__ __forceinline__ short f2bf(float f) {  // RNE fp32->bf16
  union { float f; unsigned u; } v; v.f = f;
  unsigned u = v.u;
  return (short)((u + 0x7FFFu + ((u >> 16) & 1u)) >> 16);
}

// ---------------- K1: emissions partial GEMV ----------------
__global__ __launch_bounds__(256) void emis_part_kernel(
    const float* __restrict__ hidden, const float* __restrict__ W,
    float* __restrict__ part) {
  __shared__ __align__(16) float hid[64 * 68];
  __shared__ __align__(16) float red[4 * 64 * 33];

  const int tid = threadIdx.x;
  const int wv = __builtin_amdgcn_readfirstlane(tid >> 6);
  const int lane = tid & 63;
  const int rowgroup = blockIdx.x >> 1;
  const int kh = blockIdx.x & 1;
  const int row0 = rowgroup * 64;
  const int kbase = kh * 512;

  float acc[32];
#pragma unroll
  for (int t = 0; t < 32; ++t) acc[t] = 0.f;

  for (int c = 0; c < 8; ++c) {
#pragma unroll
    for (int p = 0; p < 4; ++p) {
      int f = tid + 256 * p;
      int r = f >> 4, q4 = f & 15;
      const float4 v = *(const float4*)(hidden + (size_t)(row0 + r) * Hh + kbase + c * 64 + q4 * 4);
      *(float4*)&hid[r * 68 + q4 * 4] = v;
    }
    __syncthreads();
#pragma unroll
    for (int q = 0; q < 4; ++q) {
      const float4 hv = *(const float4*)&hid[lane * 68 + 16 * wv + 4 * q];
      const float hvv[4] = {hv.x, hv.y, hv.z, hv.w};
#pragma unroll
      for (int u = 0; u < 4; ++u) {
        const int h = 16 * wv + 4 * q + u;
        const float* wrow = W + (size_t)(kbase + c * 64 + h) * Tt;
#pragma unroll
        for (int t = 0; t < 32; ++t) acc[t] = fmaf(hvv[u], wrow[t], acc[t]);
      }
    }
    __syncthreads();
  }
#pragma unroll
  for (int t = 0; t < 32; ++t) red[(wv * 64 + lane) * 33 + t] = acc[t];
  __syncthreads();
#pragma unroll
  for (int p = 0; p < 8; ++p) {
    int e = tid + 256 * p;
    int r = e >> 5, t = e & 31;
    float v = red[r * 33 + t] + red[(64 + r) * 33 + t] +
              red[(128 + r) * 33 + t] + red[(192 + r) * 33 + t];
    part[(size_t)kh * PARTN + (size_t)row0 * Tt + e] = v;
  }
}

// ---------------- K2: softmax + numerator (block-reduced atomics) ----------------
__global__ __launch_bounds__(256) void softmax_num_kernel(
    const float* __restrict__ part, const float* __restrict__ bias,
    const float* __restrict__ start_trans, const float* __restrict__ trans,
    const int* __restrict__ tags, const int* __restrict__ mask,
    float* __restrict__ logem, float* __restrict__ pem,
    float* __restrict__ numb, int* __restrict__ lenw) {
  __shared__ float cbuf[8];
  __shared__ int lbuf[8];
  const int tid = threadIdx.x;
  const int lane = tid & 63;
  const int j = lane & 31, half = lane >> 5;
  const int wv = tid >> 6;
  const int r8 = blockIdx.x * 8;
  const int row = r8 + wv * 2 + half;

  float L = part[(size_t)row * Tt + j] + part[PARTN + (size_t)row * Tt + j] + bias[j];
  float mx = L;
#pragma unroll
  for (int d = 16; d >= 1; d >>= 1) mx = fmaxf(mx, __shfl_xor(mx, d, 32));
  float se = __expf(L - mx);
#pragma unroll
  for (int d = 16; d >= 1; d >>= 1) se += __shfl_xor(se, d, 32);
  const float corr = mx + __logf(se);
  const float lg = L - corr;
  logem[(size_t)row * Tt + j] = lg;
  pem[(size_t)row * Tt + j] = __expf(lg);

  const int m = mask[row];
  const int tg = tags[row];
  const float emit = __shfl(lg, tg, 32);
  if (j == 0) {
    const int srow = row & (Ss - 1);
    float contrib = 0.f;
    if (m) {
      contrib = emit;
      if (srow > 0) contrib += trans[tags[row - 1] * Tt + tg];
    }
    if (srow == 0) contrib += start_trans[tg];
    cbuf[wv * 2 + half] = contrib;
    lbuf[wv * 2 + half] = m;
  }
  __syncthreads();
  if (tid == 0) {
    float cs = 0.f; int ls = 0;
#pragma unroll
    for (int q = 0; q < 8; ++q) { cs += cbuf[q]; ls += lbuf[q]; }
    const int b = r8 >> 9;
    atomicAdd(numb + b, cs);
    atomicAdd(lenw + b, ls);
  }
}

// ---------------- K3: chunk transfer matrices via MFMA ----------------
// grid 256 x 256thr: wave = one (b,cc) chunk. P(32x32) = tiles d00,d01,d10,d11.
// Step: P <- (P · Etr) ∘ em_cols. A-frag: A[m=lane&15][k=(lane>>4)*8+j];
// C/D: col=lane&15, row=(lane>>4)*4+reg (guide §3, verified m89/m91).
__global__ __launch_bounds__(256) void chunk_kernel(
    const float* __restrict__ pem, const float* __restrict__ trans,
    const int* __restrict__ lenw, float* __restrict__ ecT,
    float* __restrict__ moff) {
  __shared__ __align__(16) float Pbuf[4 * 32 * 36];  // per-wave 32x32 pitch36
  const int tid = threadIdx.x;
  const int wv = tid >> 6, lane = tid & 63;
  const int n = lane & 15, q = lane >> 4;
  const int chunk = blockIdx.x * 4 + wv;
  const int b = chunk >> 5, cc = chunk & 31;
  float* P = Pbuf + wv * 32 * 36;

  // Etr fragments (fp32, scaled by em each step): etr[c][j] = exp(trans[8q+j][16c+n])
  float etr0[8], etr1[8];
#pragma unroll
  for (int jj = 0; jj < 8; ++jj) {
    etr0[jj] = __expf(trans[(8 * q + jj) * 32 + n]);
    etr1[jj] = __expf(trans[(8 * q + jj) * 32 + 16 + n]);
  }

  const int len = lenw[b];
  const int t0 = 1 + cc * CHUNK_L;
  int nst = (len < Ss ? len : Ss) - t0;
  nst = nst < 0 ? 0 : (nst > CHUNK_L ? CHUNK_L : nst);
  const int rowbase = b * Ss + t0;

  // A fragments: identity P
  bf16x8 a0, a1;
#pragma unroll
  for (int jj = 0; jj < 8; ++jj) {
    a0[jj] = (n == 8 * q + jj) ? (short)0x3F80 : (short)0;
    a1[jj] = (16 + n == 8 * q + jj) ? (short)0x3F80 : (short)0;
  }

  f32x4 d00, d01, d10, d11;
  if (nst == 0) {  // identity chunk (len <= t0)
#pragma unroll
    for (int r = 0; r < 4; ++r) {
      d00[r] = (4 * q + r == n) ? 1.f : 0.f;
      d01[r] = 0.f;
      d10[r] = 0.f;
      d11[r] = (4 * q + r == n) ? 1.f : 0.f;
    }
  }
  float em0 = 0.f, em1 = 0.f;
  if (nst > 0) {
    em0 = pem[(size_t)rowbase * Tt + n];
    em1 = pem[(size_t)rowbase * Tt + 16 + n];
  }
  for (int st = 0; st < nst; ++st) {
    float em0n = 0.f, em1n = 0.f;
    if (st + 1 < nst) {  // prefetch next step's em
      em0n = pem[(size_t)(rowbase + st + 1) * Tt + n];
      em1n = pem[(size_t)(rowbase + st + 1) * Tt + 16 + n];
    }
    bf16x8 bL, bR;  // B[k=8q+j][n] = Etr[k][n]*em[n]
#pragma unroll
    for (int jj = 0; jj < 8; ++jj) {
      bL[jj] = f2bf(etr0[jj] * em0);
      bR[jj] = f2bf(etr1[jj] * em1);
    }
    const f32x4 z = {0.f, 0.f, 0.f, 0.f};
    d00 = __builtin_amdgcn_mfma_f32_16x16x32_bf16(a0, bL, z, 0, 0, 0);
    d01 = __builtin_amdgcn_mfma_f32_16x16x32_bf16(a0, bR, z, 0, 0, 0);
    d10 = __builtin_amdgcn_mfma_f32_16x16x32_bf16(a1, bL, z, 0, 0, 0);
    d11 = __builtin_amdgcn_mfma_f32_16x16x32_bf16(a1, bR, z, 0, 0, 0);
    if (st + 1 < nst) {  // C-layout -> A-layout via per-wave LDS roundtrip
#pragma unroll
      for (int r = 0; r < 4; ++r) {
        P[(4 * q + r) * 36 + n] = d00[r];
        P[(4 * q + r) * 36 + 16 + n] = d01[r];
        P[(16 + 4 * q + r) * 36 + n] = d10[r];
        P[(16 + 4 * q + r) * 36 + 16 + n] = d11[r];
      }
      __builtin_amdgcn_s_waitcnt(0);  // drain DS before in-wave readback
      const float4 lo0 = *(const float4*)&P[n * 36 + 8 * q];
      const float4 lo1 = *(const float4*)&P[n * 36 + 8 * q + 4];
      const float4 hi0 = *(const float4*)&P[(16 + n) * 36 + 8 * q];
      const float4 hi1 = *(const float4*)&P[(16 + n) * 36 + 8 * q + 4];
      a0[0] = f2bf(lo0.x); a0[1] = f2bf(lo0.y); a0[2] = f2bf(lo0.z); a0[3] = f2bf(lo0.w);
      a0[4] = f2bf(lo1.x); a0[5] = f2bf(lo1.y); a0[6] = f2bf(lo1.z); a0[7] = f2bf(lo1.w);
      a1[0] = f2bf(hi0.x); a1[1] = f2bf(hi0.y); a1[2] = f2bf(hi0.z); a1[3] = f2bf(hi0.w);
      a1[4] = f2bf(hi1.x); a1[5] = f2bf(hi1.y); a1[6] = f2bf(hi1.z); a1[7] = f2bf(hi1.w);
    }
    em0 = em0n; em1 = em1n;
  }

  // Row-wise max (over cols) per row, normalize to row-max-1 + Moff = log(max).
  // Lane's rows: r0 tiles rows 4q+r; r1 tiles rows 16+4q+r. Reduce over n-lanes.
  float lg0[4], lg1[4], iv0[4], iv1[4];
#pragma unroll
  for (int r = 0; r < 4; ++r) {
    float m0v = fmaxf(d00[r], d01[r]);
    float m1v = fmaxf(d10[r], d11[r]);
#pragma unroll
    for (int d = 8; d >= 1; d >>= 1) {
      m0v = fmaxf(m0v, __shfl_xor(m0v, d, 16));
      m1v = fmaxf(m1v, __shfl_xor(m1v, d, 16));
    }
    m0v = fmaxf(m0v, 1e-37f);
    m1v = fmaxf(m1v, 1e-37f);
    lg0[r] = __logf(m0v); iv0[r] = __builtin_amdgcn_rcpf(m0v);
    lg1[r] = __logf(m1v); iv1[r] = __builtin_amdgcn_rcpf(m1v);
  }
  // ecT[b][cc][j][i]: col j contiguous in i (phase2 float4 row reads)
  float* E = ecT + (size_t)(b * NCHUNK + cc) * 32 * 32;
  {
    float4 s;
    s = make_float4(d00[0] * iv0[0], d00[1] * iv0[1], d00[2] * iv0[2], d00[3] * iv0[3]);
    *(float4*)&E[n * 32 + 4 * q] = s;
    s = make_float4(d10[0] * iv1[0], d10[1] * iv1[1], d10[2] * iv1[2], d10[3] * iv1[3]);
    *(float4*)&E[n * 32 + 16 + 4 * q] = s;
    s = make_float4(d01[0] * iv0[0], d01[1] * iv0[1], d01[2] * iv0[2], d01[3] * iv0[3]);
    *(float4*)&E[(16 + n) * 32 + 4 * q] = s;
    s = make_float4(d11[0] * iv1[0], d11[1] * iv1[1], d11[2] * iv1[2], d11[3] * iv1[3]);
    *(float4*)&E[(16 + n) * 32 + 16 + 4 * q] = s;
  }
  if (n == 0) {
    float* Mo = moff + (size_t)(b * NCHUNK + cc) * 32;
    *(float4*)&Mo[4 * q] = make_float4(lg0[0], lg0[1], lg0[2], lg0[3]);
    *(float4*)&Mo[16 + 4 * q] = make_float4(lg1[0], lg1[1], lg1[2], lg1[3]);
  }
}

// ---------------- K4: phase-2 sweep, one wave per batch ----------------
__global__ __launch_bounds__(64) void phase2_kernel(
    const float* __restrict__ logem, const float* __restrict__ start_trans,
    const float* __restrict__ end_trans, const float* __restrict__ ecT,
    const float* __restrict__ moff, const float* __restrict__ numb,
    const int* __restrict__ lenw, const int* __restrict__ tags,
    float* __restrict__ out) {
  const int b = blockIdx.x;
  const int lane = threadIdx.x;
  const int j = lane & 31;
  __shared__ __align__(16) float qlds[32];

  const float* base = ecT + (size_t)b * NCHUNK * 32 * 32;
  const float* mbase = moff + (size_t)b * NCHUNK * 32;

  float4 M[8], N[8];
  const float* r0 = base + j * 32;
#pragma unroll
  for (int k = 0; k < 8; ++k) M[k] = *(const float4*)(r0 + 4 * k);
  float mo_cur = mbase[j];

  float al0 = start_trans[j] + logem[(size_t)b * Ss * Tt + j];
  float m0 = al0;
#pragma unroll
  for (int d = 16; d >= 1; d >>= 1) m0 = fmaxf(m0, __shfl_xor(m0, d, 32));
  float a = __expf(al0 - m0);
  float Mb = m0;
  const float eend = __expf(end_trans[j]);

  float mo_next = 0.f;
  for (int c = 0; c < NCHUNK; ++c) {
    if (c + 1 < NCHUNK) {
      const float* rn = base + ((c + 1) * 32 + j) * 32;
#pragma unroll
      for (int k = 0; k < 8; ++k) N[k] = *(const float4*)(rn + 4 * k);
      mo_next = mbase[(c + 1) * 32 + j];
    }
    float mom = mo_cur;
#pragma unroll
    for (int d = 16; d >= 1; d >>= 1) mom = fmaxf(mom, __shfl_xor(mom, d, 32));
    float q = a * __expf(mo_cur - mom);
    if (lane < 32) qlds[j] = q;
    __builtin_amdgcn_s_waitcnt(0);
    float s = 0.f;
#pragma unroll
    for (int k = 0; k < 8; ++k) {
      const float4 q4 = *(const float4*)(qlds + 4 * k);
      s = fmaf(q4.x, M[k].x, s);
      s = fmaf(q4.y, M[k].y, s);
      s = fmaf(q4.z, M[k].z, s);
      s = fmaf(q4.w, M[k].w, s);
    }
    float m = s;
#pragma unroll
    for (int d = 16; d >= 1; d >>= 1) m = fmaxf(m, __shfl_xor(m, d, 32));
    m = fmaxf(m, 1e-30f);
    a = s * __builtin_amdgcn_rcpf(m);
    Mb += mom + __logf(m);
#pragma unroll
    for (int k = 0; k < 8; ++k) M[k] = N[k];
    mo_cur = mo_next;
  }
  float z = a * eend;
#pragma unroll
  for (int d = 16; d >= 1; d >>= 1) z += __shfl_xor(z, d, 32);
  if (lane == 0) {
    const int len = lenw[b];
    const float numfull = numb[b] + end_trans[tags[b * Ss + len - 1]];
    const float denom = Mb + __logf(z);
    atomicAdd(out, -(numfull - denom) * (1.0f / 32.0f));
  }
}

extern "C" void kernel_launch(void* const* d_in, const int* in_sizes, int n_in,
                              void* d_out, int out_size, void* d_ws, size_t ws_size,
                              hipStream_t stream) {
  const float* hidden = (const float*)d_in[0];
  const float* W = (const float*)d_in[1];
  const float* bias = (const float*)d_in[2];
  const float* start_trans = (const float*)d_in[3];
  const float* end_trans = (const float*)d_in[4];
  const float* trans = (const float*)d_in[5];
  const int* tags = (const int*)d_in[6];
  const int* mask = (const int*)d_in[7];
  float* out = (float*)d_out;

  float* part = (float*)d_ws;                        // 2*524288
  float* ecT = part;                                 // aliases part (dead after K2)
  float* moff = part + 2 * PARTN;                    // 32768
  float* logem = moff + (size_t)Bb * NCHUNK * 32;    // 524288
  float* pem = logem + PARTN;                        // 524288
  float* numb = pem + PARTN;                         // 32
  int* lenw = (int*)(numb + Bb);                     // 32

  hipMemsetAsync(out, 0, sizeof(float), stream);
  hipMemsetAsync(numb, 0, 64 * sizeof(float), stream);  // numb + lenw
  emis_part_kernel<<<512, 256, 0, stream>>>(hidden, W, part);
  softmax_num_kernel<<<NROWS / 8, 256, 0, stream>>>(part, bias, start_trans,
                                                    trans, tags, mask, logem,
                                                    pem, numb, lenw);
  chunk_kernel<<<Bb * NCHUNK / 4, 256, 0, stream>>>(pem, trans, lenw, ecT, moff);
  phase2_kernel<<<Bb, 64, 0, stream>>>(logem, start_trans, end_trans, ecT, moff,
                                       numb, lenw, tags, out);
}